// Round 4
// baseline (56.463 us; speedup 1.0000x reference)
//
#include <hip/hip_runtime.h>
#include <math.h>

// S4D layer B=8,H=512,L=2048,N=64 via chunked state-space + MFMA.
// R4 = R2 passing body + split tables (3-term products) + diagonal folded to
// f32 epilogue + exact rho ladder + f32 E table aliased over w/S pool.

typedef short bf16x8 __attribute__((ext_vector_type(8)));
typedef float f32x4  __attribute__((ext_vector_type(4)));

#define NCHK 32
#define USTR 68   // f32 row stride for u/w/S tiles
#define ESTR 66   // f32 row stride for E table (aliased, setup-only)
#define MFMA __builtin_amdgcn_mfma_f32_16x16x32_bf16

static __device__ __forceinline__ short f2bf(float x){
    unsigned u = __float_as_uint(x);
    u += 0x7FFFu + ((u >> 16) & 1u);          // RNE
    return (short)(u >> 16);
}
static __device__ __forceinline__ float bf2f(short h){
    return __uint_as_float(((unsigned)(unsigned short)h) << 16);
}
static __device__ __forceinline__ void split8(const float* f, bf16x8& hi, bf16x8& lo){
    #pragma unroll
    for (int i=0;i<8;++i){
        const short hv = f2bf(f[i]);
        hi[i] = hv;
        lo[i] = f2bf(f[i] - bf2f(hv));
    }
}
static __device__ __forceinline__ void cmul(float& xr, float& xi, float yr, float yi){
    const float t = xr*yr - xi*yi;
    xi = xr*yi + xi*yr;
    xr = t;
}

__global__ void __launch_bounds__(256, 3) s4d_mfma4(
    const float* __restrict__ u_g, const float* __restrict__ A_re,
    const float* __restrict__ A_im, const float* __restrict__ Cg,
    const float* __restrict__ Dp, const float* __restrict__ log_step,
    float* __restrict__ out, int B, int H, int L)
{
    const int h    = blockIdx.x;
    const int tid  = threadIdx.x;
    const int wv   = tid >> 6;
    const int lane = tid & 63;
    const int l15  = lane & 15;
    const int oct  = lane >> 4;

    __shared__ __align__(16) float u_s[2][NCHK][USTR];    // f32 u, double-buffered
    __shared__ __align__(16) char  pool2[34816];          // loop: w_s|S_s ; setup: E table
    __shared__ float K_s[64];

    float (*w_s)[NCHK][USTR] = (float (*)[NCHK][USTR])pool2;             // [2][32][68]
    float (*S_s)[NCHK][USTR] = (float (*)[NCHK][USTR])(pool2 + 17408);   // [2][32][68]
    float* Ef = (float*)pool2;        // rows: p -> Re(c r^p) at p*66 ; -Im at (65+p)*66

    const float dt = expf(log_step[h]);

    // ---- per-lane (n = lane) params ----
    const float are = fminf(A_re[h*64 + lane], -1e-4f);
    const float aim = A_im[h*64 + lane];
    const float dre = dt * are, dim = dt * aim;
    float sn_, cs_;
    const float er = expf(dre);
    sincosf(dim, &sn_, &cs_);
    const float rre = er * cs_, rim = er * sn_;          // r = exp(dtA)
    const float den = are*are + aim*aim;
    const float ir  = are/den, ii = -aim/den;            // 1/A
    const float c0r = Cg[(h*64+lane)*2 + 0];
    const float c0i = Cg[(h*64+lane)*2 + 1];
    const float e1r = rre - 1.0f, e1i = rim;
    const float ttr = e1r*ir - e1i*ii;
    const float tti = e1r*ii + e1i*ir;
    const float cre = c0r*ttr - c0i*tti;                 // c = Cc*(exp(dtA)-1)/A
    const float cim = c0r*tti + c0i*ttr;

    // ---- stage u(b=0) (f32, as R2) ----
    {
        const float* up = u_g + (size_t)h * (size_t)L;
        float4 a0 = *(const float4*)(up + tid*8);
        float4 a1 = *(const float4*)(up + tid*8 + 4);
        const int ch = (tid*8) >> 6, t0 = (tid*8) & 63;
        *(float4*)&u_s[0][ch][t0]   = a0;
        *(float4*)&u_s[0][ch][t0+4] = a1;
    }

    // ---- build E[p][n] = c_n r_n^p (f32) and K[d]; rho = r^64 exact ladder ----
    float rhor, rhoi;
    {
        float qre = rre, qim = rim;                      // -> r^16 by squaring
        #pragma unroll
        for (int i=0;i<4;++i){ const float t2=qre*qre-qim*qim; qim=2.0f*qre*qim; qre=t2; }
        rhor = qre; rhoi = qim;                          // r^64 = ((r^16)^2)^2
        cmul(rhor, rhoi, rhor, rhoi);
        cmul(rhor, rhoi, rhor, rhoi);
        float wre = 1.0f, wim = 0.0f;                    // r^(16*wv)
        for (int i=0;i<wv;++i) cmul(wre, wim, qre, qim);
        float mre = cre*wre - cim*wim;
        float mim = cre*wim + cim*wre;                   // c * r^(16wv)
        #pragma unroll
        for (int jj=0;jj<16;++jj){
            const int p = wv*16 + jj;
            float red = mre;
            #pragma unroll
            for (int off=32; off; off>>=1) red += __shfl_xor(red, off);
            if (lane == 0) K_s[p] = red;                 // K[p] = Re sum_n c r^p
            Ef[p*ESTR + lane]      = mre;                // Re(c r^p)
            Ef[(65+p)*ESTR + lane] = -mim;               // -Im(c r^p)
            cmul(mre, mim, rre, rim);
        }
        if (wv == 3){
            Ef[64*ESTR + lane]      = mre;               // p = 64
            Ef[(65+64)*ESTR + lane] = -mim;
        }
    }
    __syncthreads();

    // ---- register table fragments (A-operands), hi/lo split ----
    bf16x8 Whre[2], Wlre[2], Whim[2], Wlim[2];
    bf16x8 Mhre[2], Mlre[2], Mhni[2], Mlni[2];
    bf16x8 Th[2],  Tl[2];
    {
        const int nw = wv*16 + l15;
        const float aw = fminf(A_re[h*64+nw], -1e-4f);
        const float bw = A_im[h*64+nw];
        const float dr = dt*aw, di = dt*bw;
        float s1, c1; const float e1 = expf(dr); sincosf(di, &s1, &c1);
        const float rwr = e1*c1, rwi = e1*s1;            // r_nw
        #pragma unroll
        for (int kh=0; kh<2; ++kh){
            const int elo = 63 - (kh*32 + oct*8) - 7;    // exponent at i=7
            float s2, c2;
            const float e2 = expf(dr*(float)elo); sincosf(di*(float)elo, &s2, &c2);
            float vr = e2*c2, vi = e2*s2;                // r^elo
            float fr[8], fi[8];
            fr[7] = vr; fi[7] = vi;
            #pragma unroll
            for (int i=6;i>=0;--i){
                cmul(vr, vi, rwr, rwi);
                fr[i] = vr; fi[i] = vi;
            }
            split8(fr, Whre[kh], Wlre[kh]);
            split8(fi, Whim[kh], Wlim[kh]);
        }
        const int jp1 = wv*16 + l15 + 1;                 // M[j][n] = c r^(j+1)
        #pragma unroll
        for (int kh=0; kh<2; ++kh){
            const int n0 = kh*32 + oct*8;
            float fm[8];
            #pragma unroll
            for (int i=0;i<8;++i) fm[i] = Ef[jp1*ESTR + n0 + i];
            split8(fm, Mhre[kh], Mlre[kh]);
            #pragma unroll
            for (int i=0;i<8;++i) fm[i] = Ef[(65+jp1)*ESTR + n0 + i];
            split8(fm, Mhni[kh], Mlni[kh]);
            float ft[8];
            #pragma unroll
            for (int i=0;i<8;++i){
                const int d = (wv*16 + l15) - (n0 + i);
                ft[i] = (d > 0) ? K_s[d] : 0.0f;         // diagonal (d==0) excluded
            }
            split8(ft, Th[kh], Tl[kh]);
        }
    }
    const float DK = Dp[h] + K_s[0];                     // (D + K[0]) applied in f32 epilogue
    __syncthreads();                                     // E dead; w/S live after this

    // ---- per-batch loop ----
    for (int b=0; b<B; ++b){
        const int buf = b & 1;
        const size_t obase = ((size_t)b*H + h) * (size_t)L;
        float4 p0 = {0,0,0,0}, p1 = {0,0,0,0};
        const bool pf = (b+1 < B);
        if (pf){
            const float* up = u_g + ((size_t)(b+1)*H + h) * (size_t)L;
            p0 = *(const float4*)(up + tid*8);
            p1 = *(const float4*)(up + tid*8 + 4);
        }
        // per-wave U hi/lo split from f32 LDS (R2 style)
        bf16x8 Uh[2][2], Ul[2][2];
        #pragma unroll
        for (int ct=0; ct<2; ++ct){
            const int ch = ct*16 + l15;
            #pragma unroll
            for (int kh=0; kh<2; ++kh){
                const float4 x0 = *(const float4*)&u_s[buf][ch][kh*32 + oct*8];
                const float4 x1 = *(const float4*)&u_s[buf][ch][kh*32 + oct*8 + 4];
                const float f[8] = {x0.x,x0.y,x0.z,x0.w,x1.x,x1.y,x1.z,x1.w};
                split8(f, Uh[ct][kh], Ul[ct][kh]);
            }
        }
        // phase A: w[n,k] = sum_t r^(63-t) u[64k+t]  (3-term)
        #pragma unroll
        for (int ct=0; ct<2; ++ct){
            f32x4 ar = {0.f,0.f,0.f,0.f}, ai = {0.f,0.f,0.f,0.f};
            #pragma unroll
            for (int kh=0; kh<2; ++kh){
                ar = MFMA(Whre[kh], Uh[ct][kh], ar, 0,0,0);
                ar = MFMA(Whre[kh], Ul[ct][kh], ar, 0,0,0);
                ar = MFMA(Wlre[kh], Uh[ct][kh], ar, 0,0,0);
                ai = MFMA(Whim[kh], Uh[ct][kh], ai, 0,0,0);
                ai = MFMA(Whim[kh], Ul[ct][kh], ai, 0,0,0);
                ai = MFMA(Wlim[kh], Uh[ct][kh], ai, 0,0,0);
            }
            const int ch = ct*16 + l15;
            const int n0 = wv*16 + oct*4;
            *(f32x4*)&w_s[0][ch][n0] = ar;
            *(f32x4*)&w_s[1][ch][n0] = ai;
        }
        __syncthreads();
        // phase B: scan (wave 0, lane = n), S stored f32
        if (wv == 0){
            float sr = 0.0f, si = 0.0f;
            #pragma unroll 4
            for (int k=0;k<NCHK;++k){
                S_s[0][k][lane] = sr; S_s[1][k][lane] = si;   // S[k-1]
                const float wr = w_s[0][k][lane];
                const float wi = w_s[1][k][lane];
                const float t2 = fmaf(rhor, sr, fmaf(-rhoi, si, wr));
                si = fmaf(rhor, si, fmaf(rhoi, sr, wi));
                sr = t2;
            }
        }
        __syncthreads();
        // phase C: y = Re(M S[k-1]) + T u  (3-term) + (D + K0) u  (f32)
        #pragma unroll
        for (int ct=0; ct<2; ++ct){
            const int ch = ct*16 + l15;
            bf16x8 Srh[2], Srl[2], Sih[2], Sil[2];
            #pragma unroll
            for (int kh=0; kh<2; ++kh){
                {
                    const float4 x0 = *(const float4*)&S_s[0][ch][kh*32+oct*8];
                    const float4 x1 = *(const float4*)&S_s[0][ch][kh*32+oct*8+4];
                    const float f[8] = {x0.x,x0.y,x0.z,x0.w,x1.x,x1.y,x1.z,x1.w};
                    split8(f, Srh[kh], Srl[kh]);
                }
                {
                    const float4 x0 = *(const float4*)&S_s[1][ch][kh*32+oct*8];
                    const float4 x1 = *(const float4*)&S_s[1][ch][kh*32+oct*8+4];
                    const float f[8] = {x0.x,x0.y,x0.z,x0.w,x1.x,x1.y,x1.z,x1.w};
                    split8(f, Sih[kh], Sil[kh]);
                }
            }
            f32x4 acc = {0.f,0.f,0.f,0.f};
            #pragma unroll
            for (int kh=0; kh<2; ++kh){
                acc = MFMA(Mhre[kh], Srh[kh], acc, 0,0,0);
                acc = MFMA(Mhre[kh], Srl[kh], acc, 0,0,0);
                acc = MFMA(Mlre[kh], Srh[kh], acc, 0,0,0);
                acc = MFMA(Mhni[kh], Sih[kh], acc, 0,0,0);
                acc = MFMA(Mhni[kh], Sil[kh], acc, 0,0,0);
                acc = MFMA(Mlni[kh], Sih[kh], acc, 0,0,0);
                acc = MFMA(Th[kh], Uh[ct][kh], acc, 0,0,0);
                acc = MFMA(Th[kh], Ul[ct][kh], acc, 0,0,0);
                acc = MFMA(Tl[kh], Uh[ct][kh], acc, 0,0,0);
            }
            const int j0 = wv*16 + oct*4;
            const float4 uu = *(const float4*)&u_s[buf][ch][j0];
            float4 y;
            y.x = acc[0] + DK*uu.x;
            y.y = acc[1] + DK*uu.y;
            y.z = acc[2] + DK*uu.z;
            y.w = acc[3] + DK*uu.w;
            *(float4*)(out + obase + (size_t)(ch*64 + j0)) = y;
        }
        // commit prefetched u (f32)
        if (pf){
            const int ch2 = (tid*8) >> 6, t0 = (tid*8) & 63;
            *(float4*)&u_s[buf^1][ch2][t0]   = p0;
            *(float4*)&u_s[buf^1][ch2][t0+4] = p1;
        }
        __syncthreads();
    }
}

extern "C" void kernel_launch(void* const* d_in, const int* in_sizes, int n_in,
                              void* d_out, int out_size, void* d_ws, size_t ws_size,
                              hipStream_t stream) {
    const float* u        = (const float*)d_in[0];
    const float* A_re     = (const float*)d_in[1];
    const float* A_im     = (const float*)d_in[2];
    const float* C        = (const float*)d_in[3];
    const float* Dp       = (const float*)d_in[4];
    const float* log_step = (const float*)d_in[5];
    float* out = (float*)d_out;

    const int H = in_sizes[4];                 // 512
    const int L = 2048;                        // fixed by problem
    const int B = in_sizes[0] / (H * L);       // 8
    (void)d_ws; (void)ws_size; (void)out_size; (void)n_in;

    dim3 grid(H);
    dim3 block(256);
    hipLaunchKernelGGL(s4d_mfma4, grid, block, 0, stream,
                       u, A_re, A_im, C, Dp, log_step, out, B, H, L);
}